// Round 4
// baseline (604.597 us; speedup 1.0000x reference)
//
#include <hip/hip_runtime.h>
#include <hip/hip_bf16.h>
#include <hip/hip_fp16.h>

typedef unsigned int u32;
typedef unsigned short u16;
typedef __bf16 bf16x8 __attribute__((ext_vector_type(8)));
typedef float floatx4 __attribute__((ext_vector_type(4)));

#define SCALE 0.08838834764831845f
#define FETCH_MAX 204

__device__ __forceinline__ float bf2f(u16 u) {
    union { u32 i; float f; } v; v.i = ((u32)u) << 16; return v.f;
}
__device__ __forceinline__ u16 f2bf(float f) {
    union { float f; u32 i; } v; v.f = f;
    u32 r = v.i + 0x7FFFu + ((v.i >> 16) & 1u);
    return (u16)(r >> 16);
}
__device__ __forceinline__ u16 f2h_bits(float f) {
    __half h = __float2half(f);
    union { __half h; u16 u; } v; v.h = h; return v.u;
}
__device__ __forceinline__ float h_bits2f(u16 u) {
    union { __half h; u16 u; } v; v.u = u; return __half2float(v.h);
}
__device__ __forceinline__ u32 h2key(u16 hb) {     // order-preserving fp16 -> u16 key
    return (u32)(u16)(hb ^ ((hb & 0x8000u) ? 0xFFFFu : 0x8000u));
}
__device__ __forceinline__ u16 key2h(u32 k) {      // inverse of h2key
    return (u16)((k & 0x8000u) ? (k ^ 0x8000u) : (k ^ 0xFFFFu));
}
// async global->LDS, 16B per lane; LDS dest must be wave-uniform base + lane*16
__device__ __forceinline__ void gld_lds16(const void* g, void* l) {
    __builtin_amdgcn_global_load_lds(
        (const __attribute__((address_space(1))) void*)g,
        (__attribute__((address_space(3))) void*)l, 16, 0, 0);
}

// ---------------------------------------------------------------- detect input dtype
__global__ void detect_k(const u32* cosw, int* flag) {
    if (threadIdx.x == 0 && blockIdx.x == 0)
        *flag = (cosw[0] == 0x3F800000u) ? 1 : 0;   // 1 = inputs are fp32
}

__global__ __launch_bounds__(256) void zero_k(int* p, int n) {
    int i = blockIdx.x * 256 + threadIdx.x;
    if (i < n) p[i] = 0;
}

// ---------------------------------------------------------------- convert (fp32 -> bf16), only when flag==1
__global__ __launch_bounds__(256) void convert_k(
    const int* flagp, const float* hs, const float* wq, const float* wk,
    const float* wv, const float* wo,
    u16* chs, u16* cwq, u16* cwk, u16* cwv, u16* cwo)
{
    if (*flagp == 0) return;
    const long S0 = 4194304/4, S1 = 16777216/4, S2 = 4194304/4, S3 = 4194304/4, S4 = 16777216/4;
    const long total = S0+S1+S2+S3+S4;
    for (long idx = (long)blockIdx.x*256 + threadIdx.x; idx < total; idx += (long)gridDim.x*256) {
        const float* src; u16* dst; long o = idx;
        if (o < S0)            { src = hs; dst = chs; }
        else if ((o -= S0) < S1) { src = wq; dst = cwq; }
        else if ((o -= S1) < S2) { src = wk; dst = cwk; }
        else if ((o -= S2) < S3) { src = wv; dst = cwv; }
        else                   { o -= S3; src = wo; dst = cwo; }
        float4 v = ((const float4*)src)[o];
        u32 lo = (u32)f2bf(v.x) | ((u32)f2bf(v.y) << 16);
        u32 hi = (u32)f2bf(v.z) | ((u32)f2bf(v.w) << 16);
        ((uint2*)dst)[o] = make_uint2(lo, hi);
    }
}

// ---------------------------------------------------------------- GEMM  C[M,N] = A[M,K] * B[N,K]^T
// m97 structure: linear [128][64] LDS + global_load_lds width-16 staging (no VGPR
// round-trip). Staging lane order is base + lane*16, matching the HW's wave-uniform
// LDS dest rule. Linear-layout ds_read conflicts are the known m97 tradeoff.
__global__ __launch_bounds__(256) void gemm_bt(
    const int* flagp,
    const u16* A0, const u16* A1,
    const u16* B0a, const u16* B0b,
    const u16* B1a, const u16* B1b,
    const u16* B2a, const u16* B2b,
    int n0, int n1,
    u16* Cb, float* Cf,
    int M, int N, int K, int ldc)
{
    const int flag = *flagp;
    const u16* A  = flag ? A1 : A0;
    const u16* Bq = flag ? B0b : B0a;
    const u16* Bk = flag ? B1b : B1a;
    const u16* Bv = flag ? B2b : B2a;
    __shared__ u16 Al[128][64];
    __shared__ u16 Bl[128][64];
    const int tid = threadIdx.x;
    const int wave = tid >> 6, lane = tid & 63;
    const int qd = lane >> 4, l16 = lane & 15;
    const int wm = wave & 1, wn = wave >> 1;
    const int m0 = blockIdx.y * 128, nb = blockIdx.x * 128;
    floatx4 acc[4][4];
    floatx4 zf = {0.f, 0.f, 0.f, 0.f};
    for (int mt = 0; mt < 4; ++mt) for (int nt = 0; nt < 4; ++nt) acc[mt][nt] = zf;

    for (int k0 = 0; k0 < K; k0 += 64) {
        #pragma unroll
        for (int it = 0; it < 4; ++it) {
            int idx = tid + it*256;
            int r = idx >> 3, c8 = idx & 7;
            gld_lds16(&A[(size_t)(m0 + r)*K + k0 + c8*8], &Al[r][c8*8]);
            int f = nb + r;
            const u16* Brow = (f < n0) ? (Bq + (size_t)f*K)
                             : (f < n0 + n1) ? (Bk + (size_t)(f - n0)*K)
                             : (Bv + (size_t)(f - n0 - n1)*K);
            gld_lds16(&Brow[k0 + c8*8], &Bl[r][c8*8]);
        }
        __syncthreads();
        #pragma unroll
        for (int ks = 0; ks < 2; ++ks) {
            bf16x8 af[4], bfr[4];
            #pragma unroll
            for (int mt = 0; mt < 4; ++mt)
                af[mt] = *(const bf16x8*)&Al[wm*64 + mt*16 + l16][ks*32 + qd*8];
            #pragma unroll
            for (int nt = 0; nt < 4; ++nt)
                bfr[nt] = *(const bf16x8*)&Bl[wn*64 + nt*16 + l16][ks*32 + qd*8];
            #pragma unroll
            for (int mt = 0; mt < 4; ++mt)
                #pragma unroll
                for (int nt = 0; nt < 4; ++nt)
                    acc[mt][nt] = __builtin_amdgcn_mfma_f32_16x16x32_bf16(af[mt], bfr[nt], acc[mt][nt], 0, 0, 0);
        }
        __syncthreads();
    }
    const bool of32 = (Cf != nullptr) && flag;
    #pragma unroll
    for (int mt = 0; mt < 4; ++mt)
        #pragma unroll
        for (int nt = 0; nt < 4; ++nt)
            #pragma unroll
            for (int rg = 0; rg < 4; ++rg) {
                int row = m0 + wm*64 + mt*16 + qd*4 + rg;   // C: row=(lane>>4)*4+reg
                int col = nb + wn*64 + nt*16 + l16;         //    col=lane&15
                float v = acc[mt][nt][rg];
                if (of32) Cf[(size_t)row*ldc + col] = v;
                else      Cb[(size_t)row*ldc + col] = f2bf(v);
            }
}

// ---------------------------------------------------------------- RoPE in-place on Q (slots 0..31) and K (32..39)
__global__ __launch_bounds__(256) void rope_k(const int* flagp, u16* QKV,
                                              const void* cosp, const void* sinp)
{
    const int flag = *flagp;
    long idx = (long)blockIdx.x*256 + threadIdx.x;   // 1024*40*64
    int d = (int)(idx & 63);
    int t = (int)(idx >> 6);
    int slot = t % 40, i = t / 40;
    int col0 = (slot < 32) ? slot*128 : 4096 + (slot - 32)*128;
    size_t base = (size_t)i*6144 + col0;
    float q1 = bf2f(QKV[base + d]), q2 = bf2f(QKV[base + d + 64]);
    float c, s;
    if (flag) { c = ((const float*)cosp)[i*128 + d]; s = ((const float*)sinp)[i*128 + d]; }
    else      { c = bf2f(((const u16*)cosp)[i*128 + d]); s = bf2f(((const u16*)sinp)[i*128 + d]); }
    QKV[base + d]      = f2bf(q1*c - q2*s);
    QKV[base + d + 64] = f2bf(q2*c + q1*s);
}

// ---------------------------------------------------------------- V transpose: VT[g][d][j] = V[j][g][d]
__global__ __launch_bounds__(256) void vtrans_k(const u16* QKV, u16* VT)
{
    const int b = blockIdx.x;            // 256 blocks: g(8) x dblk(2) x jblk(16)
    const int g = b >> 5, db = (b >> 4) & 1, jb = b & 15;
    __shared__ u16 t[64][72];
    const int tid = threadIdx.x;
    #pragma unroll
    for (int it = 0; it < 2; ++it) {
        int idx = tid + it*256;
        int jj = idx >> 3, c8 = idx & 7;
        uint4 v = *(const uint4*)&QKV[(size_t)(jb*64 + jj)*6144 + 5120 + g*128 + db*64 + c8*8];
        *(uint4*)&t[jj][c8*8] = v;
    }
    __syncthreads();
    #pragma unroll
    for (int it = 0; it < 2; ++it) {
        int idx = tid + it*256;
        int dd = idx >> 3, c8 = idx & 7;
        u16 tmp[8];
        #pragma unroll
        for (int e = 0; e < 8; ++e) tmp[e] = t[c8*8 + e][dd];
        *(uint4*)&VT[(size_t)(g*128 + db*64 + dd)*1024 + jb*64 + c8*8] = *(uint4*)tmp;
    }
}

// ---------------------------------------------------------------- head-0 causal row max (scaled)
__global__ __launch_bounds__(256) void rowmax0_k(const u16* QKV, float* rowmax0)
{
    const int i = blockIdx.x;
    __shared__ float Qs[128];
    __shared__ float wm4[4];
    const int tid = threadIdx.x, wave = tid >> 6, lane = tid & 63;
    if (tid < 16) {
        uint4 v = *(const uint4*)&QKV[(size_t)i*6144 + tid*8];
        Qs[tid*8+0] = bf2f((u16)(v.x & 0xffff)); Qs[tid*8+1] = bf2f((u16)(v.x >> 16));
        Qs[tid*8+2] = bf2f((u16)(v.y & 0xffff)); Qs[tid*8+3] = bf2f((u16)(v.y >> 16));
        Qs[tid*8+4] = bf2f((u16)(v.z & 0xffff)); Qs[tid*8+5] = bf2f((u16)(v.z >> 16));
        Qs[tid*8+6] = bf2f((u16)(v.w & 0xffff)); Qs[tid*8+7] = bf2f((u16)(v.w >> 16));
    }
    __syncthreads();
    float mx = -3.0e38f;
    for (int j = tid; j <= i; j += 256) {
        const u16* Kr = &QKV[(size_t)j*6144 + 4096];   // kv head 0
        float acc = 0.f;
        #pragma unroll
        for (int c8 = 0; c8 < 16; ++c8) {
            uint4 v = *(const uint4*)&Kr[c8*8];
            acc += Qs[c8*8+0]*bf2f((u16)(v.x & 0xffff)) + Qs[c8*8+1]*bf2f((u16)(v.x >> 16));
            acc += Qs[c8*8+2]*bf2f((u16)(v.y & 0xffff)) + Qs[c8*8+3]*bf2f((u16)(v.y >> 16));
            acc += Qs[c8*8+4]*bf2f((u16)(v.z & 0xffff)) + Qs[c8*8+5]*bf2f((u16)(v.z >> 16));
            acc += Qs[c8*8+6]*bf2f((u16)(v.w & 0xffff)) + Qs[c8*8+7]*bf2f((u16)(v.w >> 16));
        }
        mx = fmaxf(mx, acc * SCALE);
    }
    #pragma unroll
    for (int off = 1; off < 64; off <<= 1) mx = fmaxf(mx, __shfl_xor(mx, off, 64));
    if (lane == 0) wm4[wave] = mx;
    __syncthreads();
    if (tid == 0) rowmax0[i] = fmaxf(fmaxf(wm4[0], wm4[1]), fmaxf(wm4[2], wm4[3]));
}

// ---------------------------------------------------------------- scores (MFMA, direct-global) -> Sg fp16 + count
// v2: scores buffered in LDS, flushed with coalesced uint4 stores (the v1 scalar
// u16 global stores -- up to 64/thread -- were the +39us regression vs qk_count).
// Count still taken on the in-register fp32 values: bitwise-identical selection.
// Ragged layout: per (h,rb): 16 rows x jtc*64 fp16; jtc(rb)=(rb>>2)+1;
// prefix(rb)=jtc*(2*(rb>>2)+(rb&3)) row-tiles of 1024 elems; per head sum = 544*1024.
__global__ __launch_bounds__(256) void score_count(
    const u16* QKV, const float* rowmax0, int* count_sum, u16* Sg)
{
    const int bid = blockIdx.x;
    const int h = bid >> 6, rb = 63 - (bid & 63);   // heavy row-blocks first
    const int r0 = rb * 16, g = h >> 2;
    const int q4 = rb >> 2, rm4 = rb & 3;
    const int jtc = q4 + 1;                          // == (r0+16+63)>>6
    const int jt64 = jtc * 64;
    const size_t sbase = ((size_t)h*544 + (size_t)jtc*(2*q4 + rm4)) * 1024;
    const int tid = threadIdx.x, wave = tid >> 6, lane = tid & 63;
    const int qd = lane >> 4, l16 = lane & 15;
    __shared__ u16 SP[16][1032];
    __shared__ int redcnt[4][16];

    bf16x8 af[4];
    #pragma unroll
    for (int ks = 0; ks < 4; ++ks)
        af[ks] = *(const bf16x8*)&QKV[(size_t)(r0 + l16)*6144 + h*128 + ks*32 + qd*8];

    float rm0[4]; int runcnt[4];
    #pragma unroll
    for (int rg = 0; rg < 4; ++rg) {
        runcnt[rg] = 0;
        rm0[rg] = rowmax0[r0 + qd*4 + rg] - 5.0f;
    }

    #pragma unroll 2
    for (int ct = 0; ct < jtc; ++ct) {
        const int jc = ct*64 + wave*16 + l16;
        floatx4 sa = {0.f, 0.f, 0.f, 0.f};
        #pragma unroll
        for (int ks = 0; ks < 4; ++ks) {
            bf16x8 bfr = *(const bf16x8*)&QKV[(size_t)jc*6144 + 4096 + g*128 + ks*32 + qd*8];
            sa = __builtin_amdgcn_mfma_f32_16x16x32_bf16(af[ks], bfr, sa, 0, 0, 0);
        }
        #pragma unroll
        for (int rg = 0; rg < 4; ++rg) {
            float s = sa[rg] * SCALE;
            int i = r0 + qd*4 + rg;
            if (jc <= i && s >= rm0[rg]) runcnt[rg]++;
            SP[qd*4 + rg][jc] = f2h_bits(s);
        }
    }
    #pragma unroll
    for (int off = 1; off < 16; off <<= 1)
        #pragma unroll
        for (int rg = 0; rg < 4; ++rg)
            runcnt[rg] += __shfl_xor(runcnt[rg], off, 64);
    if (l16 == 0)
        #pragma unroll
        for (int rg = 0; rg < 4; ++rg)
            redcnt[wave][qd*4 + rg] = runcnt[rg];
    __syncthreads();
    // coalesced flush: each wave stores 4 rows, 64 lanes x uint4 = 1KB/instr
    #pragma unroll
    for (int mm = 0; mm < 4; ++mm) {
        const int m = wave*4 + mm;
        for (int c = lane; c < jtc*8; c += 64)
            *(uint4*)&Sg[sbase + (size_t)m*jt64 + c*8] = *(const uint4*)&SP[m][c*8];
    }
    if (tid < 16) {
        int c = redcnt[0][tid] + redcnt[1][tid] + redcnt[2][tid] + redcnt[3][tid];
        atomicAdd(&count_sum[r0 + tid], c);
    }
}

// ---------------------------------------------------------------- fused: stage scores -> register top-k -> softmax -> PV
// v3: phase A (score MFMA) lives in score_count; scores stream in from Sg with
// coalesced uint4 loads. Phase B keys in 16 VGPRs; phase C reads pre-transposed VT.
__global__ __launch_bounds__(256, 4) void select_attn(
    const u16* Sg, const u16* VT, const int* count_sum, u16* attn)
{
    const int bid = blockIdx.x;
    const int h = bid >> 6, rb = 63 - (bid & 63);   // heavy row-blocks first (tail)
    const int r0 = rb * 16, g = h >> 2;
    const int q4 = rb >> 2, rm4 = rb & 3;
    const int jtc = q4 + 1;
    const int jt64 = jtc * 64;
    const size_t sbase = ((size_t)h*544 + (size_t)jtc*(2*q4 + rm4)) * 1024;
    const int tid = threadIdx.x, wave = tid >> 6, lane = tid & 63;
    const int qd = lane >> 4, l16 = lane & 15;
    __shared__ u16 SP[16][1032];     // fp16 scores, overwritten in-place with bf16 probs
    __shared__ float denom[16];

    // stage scores: each wave loads 4 rows, coalesced uint4 (div-free)
    #pragma unroll
    for (int mm = 0; mm < 4; ++mm) {
        const int m = wave*4 + mm;
        for (int c = lane; c < jtc*8; c += 64)
            *(uint4*)&SP[m][c*8] = *(const uint4*)&Sg[sbase + (size_t)m*jt64 + c*8];
    }
    __syncthreads();

    // ---- phase B: per wave-row exact top-k, keys in registers
    for (int batch = 0; batch < 4; ++batch) {
        const int m = batch*4 + wave;      // rows are wave-exclusive: no cross-wave SP hazard
        const int i = r0 + m, n = i + 1;
        const bool full = (i < FETCH_MAX);

        // load the row ONCE into 16 per-lane key registers (static indices only)
        u32 key[16];
        #pragma unroll
        for (int c = 0; c < 16; ++c) {
            u32 kk = 0u;
            if (c*64 < n) {                       // wave-uniform guard
                int j = c*64 + lane;
                u32 t = h2key(SP[m][j]);
                kk = (j < n) ? t : 0u;            // invalid -> key 0 (< any real score key)
            }
            key[c] = kk;
        }

        // row max via key max (order-preserving)
        u32 kmax = key[0];
        #pragma unroll
        for (int c = 1; c < 16; ++c) kmax = (key[c] > kmax) ? key[c] : kmax;
        #pragma unroll
        for (int off = 1; off < 64; off <<= 1) {
            u32 o = (u32)__shfl_xor((int)kmax, off, 64);
            kmax = (o > kmax) ? o : kmax;
        }
        const float rmax = h_bits2f(key2h(kmax));

        u32 Kstar = 0; int quota = 0;
        if (!full) {
            int k = count_sum[i] >> 5;            // floor(mean over 32 heads)
            if (k > FETCH_MAX) k = FETCH_MAX;
            if (k < 1) k = 1;
            // bisection on the 16-bit key, all-register: Kstar = max t with count(key>=t) >= k
            u32 t = 0;
            #pragma unroll 1
            for (int bit = 15; bit >= 0; --bit) {
                u32 tc = t | (1u << bit);
                int cnt = 0;
                #pragma unroll
                for (int c = 0; c < 16; ++c)
                    if (c*64 < n)
                        cnt += __popcll(__ballot(key[c] >= tc));
                if (cnt >= k) t = tc;
            }
            Kstar = t;                             // >=1: count(key>=1) = n >= k for !full rows
            int cntgt = 0;
            #pragma unroll
            for (int c = 0; c < 16; ++c)
                if (c*64 < n)
                    cntgt += __popcll(__ballot(key[c] > Kstar));
            quota = k - cntgt;                     // kept among keys == Kstar (>=1)
        }

        // probs (unnormalized); ties at Kstar kept by ascending index (stable argsort)
        float psum = 0.f; int eqbase = 0;
        #pragma unroll
        for (int c = 0; c < 16; ++c) {
            if (c < jtc) {                         // block-uniform: only cols phase C reads
                float p = 0.f;
                if (c*64 < n) {
                    int j = c*64 + lane;
                    bool valid = (j < n);
                    bool keep;
                    if (full) keep = valid;
                    else {
                        bool eq = valid && (key[c] == Kstar);
                        unsigned long long em = __ballot(eq);
                        int rk = eqbase + __popcll(em & ((1ull << lane) - 1ull));
                        keep = valid && ((key[c] > Kstar) || (eq && rk < quota));
                        eqbase += __popcll(em);
                    }
                    if (keep) p = __expf(h_bits2f(key2h(key[c])) - rmax);
                }
                psum += p;
                SP[m][c*64 + lane] = f2bf(p);      // zero-fills invalid cols too
            }
        }
        #pragma unroll
        for (int off = 1; off < 64; off <<= 1) psum += __shfl_xor(psum, off, 64);
        if (lane == 0) denom[m] = psum;
    }
    __syncthreads();

    // ---- phase C: PV, V^T fragments from pre-transposed VT (global, L2-resident)
    floatx4 oacc[2];
    floatx4 zf = {0.f, 0.f, 0.f, 0.f};
    oacc[0] = zf; oacc[1] = zf;
    const u16* VTg = VT + (size_t)g*128*1024;
    #pragma unroll 2
    for (int jt = 0; jt < jtc; ++jt) {
        #pragma unroll
        for (int ks = 0; ks < 2; ++ks) {
            bf16x8 pa = *(const bf16x8*)&SP[l16][jt*64 + ks*32 + qd*8];
            #pragma unroll
            for (int nt = 0; nt < 2; ++nt) {
                bf16x8 bv = *(const bf16x8*)&VTg[(size_t)(wave*32 + nt*16 + l16)*1024 + jt*64 + ks*32 + qd*8];
                oacc[nt] = __builtin_amdgcn_mfma_f32_16x16x32_bf16(pa, bv, oacc[nt], 0, 0, 0);
            }
        }
    }
    #pragma unroll
    for (int nt = 0; nt < 2; ++nt)
        #pragma unroll
        for (int rg = 0; rg < 4; ++rg) {
            int m = qd*4 + rg;
            float v = oacc[nt][rg] / denom[m];
            attn[(size_t)(r0 + m)*4096 + (h << 7) + wave*32 + nt*16 + l16] = f2bf(v);
        }
}

// ---------------------------------------------------------------- host launch
extern "C" void kernel_launch(void* const* d_in, const int* in_sizes, int n_in,
                              void* d_out, int out_size, void* d_ws, size_t ws_size,
                              hipStream_t stream)
{
    const void* hs = d_in[0];
    const void* cs = d_in[1];
    const void* sn = d_in[2];
    const void* wq = d_in[3];
    const void* wk = d_in[4];
    const void* wv = d_in[5];
    const void* wo = d_in[6];
    (void)in_sizes; (void)n_in; (void)out_size; (void)ws_size;

    unsigned char* W = (unsigned char*)d_ws;
    int*    flag  = (int*)   (W);
    int*    cnt   = (int*)   (W + 256);
    float*  rmax0 = (float*) (W + 4608);
    u16*    qkv   = (u16*)   (W + 139776);        // [1024][6144] bf16
    u16*    attn  = (u16*)   (W + 12722688);      // [1024][4096] bf16
    // converted-input buffers (only touched when inputs are fp32; flag=0 path never writes them)
    u16*    chs   = (u16*)   (W + 21111296);
    u16*    cwq   = (u16*)   (W + 29499904);
    u16*    cwk   = (u16*)   (W + 63054336);
    u16*    cwv   = (u16*)   (W + 71442944);
    u16*    cwo   = (u16*)   (W + 79831552);
    // VT[8][128][1024] bf16 (2 MB) reuses the chs region: chs is dead after the QKV GEMM.
    u16*    vt    = (u16*)   (W + 21111296);
    // ragged fp16 score buffer (34 MB = 32 heads * 544 * 1024 * 2B) reuses cwq/cwk/cwv,
    // all dead after the QKV GEMM; ends at 65.2 MB, below cwo at 79.8 MB.
    u16*    scrs  = (u16*)   (W + 29499904);

    detect_k<<<1, 64, 0, stream>>>((const u32*)cs, flag);
    convert_k<<<4096, 256, 0, stream>>>(flag, (const float*)hs, (const float*)wq,
                                        (const float*)wk, (const float*)wv, (const float*)wo,
                                        chs, cwq, cwk, cwv, cwo);
    // fused QKV projection: C[1024][6144]
    gemm_bt<<<dim3(48, 8), 256, 0, stream>>>(flag,
        (const u16*)hs, chs,
        (const u16*)wq, cwq, (const u16*)wk, cwk, (const u16*)wv, cwv,
        4096, 1024, qkv, nullptr, 1024, 6144, 4096, 6144);
    vtrans_k<<<256, 256, 0, stream>>>(qkv, vt);   // V is rope-free: safe right after GEMM
    rope_k<<<10240, 256, 0, stream>>>(flag, qkv, cs, sn);
    rowmax0_k<<<1024, 256, 0, stream>>>(qkv, rmax0);
    zero_k<<<4, 256, 0, stream>>>(cnt, 1024);
    score_count<<<2048, 256, 0, stream>>>(qkv, rmax0, cnt, scrs);
    select_attn<<<2048, 256, 0, stream>>>(scrs, vt, cnt, attn);
    // output projection
    gemm_bt<<<dim3(32, 8), 256, 0, stream>>>(flag,
        attn, attn,
        (const u16*)wo, cwo, (const u16*)wo, cwo, (const u16*)wo, cwo,
        4096, 4096, (u16*)d_out, (float*)d_out, 1024, 4096, 4096, 4096);
}

// Round 5
// 570.991 us; speedup vs baseline: 1.0589x; 1.0589x over previous
//
#include <hip/hip_runtime.h>
#include <hip/hip_bf16.h>
#include <hip/hip_fp16.h>

typedef unsigned int u32;
typedef unsigned short u16;
typedef __bf16 bf16x8 __attribute__((ext_vector_type(8)));
typedef float floatx4 __attribute__((ext_vector_type(4)));

#define SCALE 0.08838834764831845f
#define FETCH_MAX 204

__device__ __forceinline__ float bf2f(u16 u) {
    union { u32 i; float f; } v; v.i = ((u32)u) << 16; return v.f;
}
__device__ __forceinline__ u16 f2bf(float f) {
    union { float f; u32 i; } v; v.f = f;
    u32 r = v.i + 0x7FFFu + ((v.i >> 16) & 1u);
    return (u16)(r >> 16);
}
__device__ __forceinline__ u16 f2h_bits(float f) {
    __half h = __float2half(f);
    union { __half h; u16 u; } v; v.h = h; return v.u;
}
__device__ __forceinline__ float h_bits2f(u16 u) {
    union { __half h; u16 u; } v; v.u = u; return __half2float(v.h);
}
__device__ __forceinline__ u32 h2key(u16 hb) {     // order-preserving fp16 -> u16 key
    return (u32)(u16)(hb ^ ((hb & 0x8000u) ? 0xFFFFu : 0x8000u));
}
__device__ __forceinline__ u16 key2h(u32 k) {      // inverse of h2key
    return (u16)((k & 0x8000u) ? (k ^ 0x8000u) : (k ^ 0xFFFFu));
}
// async global->LDS, 16B per lane; LDS dest must be wave-uniform base + lane*16
__device__ __forceinline__ void gld_lds16(const void* g, void* l) {
    __builtin_amdgcn_global_load_lds(
        (const __attribute__((address_space(1))) void*)g,
        (__attribute__((address_space(3))) void*)l, 16, 0, 0);
}

// ---------------------------------------------------------------- detect input dtype
__global__ void detect_k(const u32* cosw, int* flag) {
    if (threadIdx.x == 0 && blockIdx.x == 0)
        *flag = (cosw[0] == 0x3F800000u) ? 1 : 0;   // 1 = inputs are fp32
}

__global__ __launch_bounds__(256) void zero_k(int* p, int n) {
    int i = blockIdx.x * 256 + threadIdx.x;
    if (i < n) p[i] = 0;
}

// ---------------------------------------------------------------- convert (fp32 -> bf16), only when flag==1
__global__ __launch_bounds__(256) void convert_k(
    const int* flagp, const float* hs, const float* wq, const float* wk,
    const float* wv, const float* wo,
    u16* chs, u16* cwq, u16* cwk, u16* cwv, u16* cwo)
{
    if (*flagp == 0) return;
    const long S0 = 4194304/4, S1 = 16777216/4, S2 = 4194304/4, S3 = 4194304/4, S4 = 16777216/4;
    const long total = S0+S1+S2+S3+S4;
    for (long idx = (long)blockIdx.x*256 + threadIdx.x; idx < total; idx += (long)gridDim.x*256) {
        const float* src; u16* dst; long o = idx;
        if (o < S0)            { src = hs; dst = chs; }
        else if ((o -= S0) < S1) { src = wq; dst = cwq; }
        else if ((o -= S1) < S2) { src = wk; dst = cwk; }
        else if ((o -= S2) < S3) { src = wv; dst = cwv; }
        else                   { o -= S3; src = wo; dst = cwo; }
        float4 v = ((const float4*)src)[o];
        u32 lo = (u32)f2bf(v.x) | ((u32)f2bf(v.y) << 16);
        u32 hi = (u32)f2bf(v.z) | ((u32)f2bf(v.w) << 16);
        ((uint2*)dst)[o] = make_uint2(lo, hi);
    }
}

// ---------------------------------------------------------------- GEMM  C[M,N] = A[M,K] * B[N,K]^T
// m97 structure + rule-21 chunk swizzle: LDS dest stays LINEAR (gld_lds requirement),
// the per-lane GLOBAL source chunk is XOR-permuted (c8 ^ r&7), and the fragment read
// applies the same XOR. Restores conflict-free-equivalent ds_read_b128 (8-way = LDS
// BW floor) that R4's unpadded linear layout lost (16-way), keeping the staging win.
__global__ __launch_bounds__(256) void gemm_bt(
    const int* flagp,
    const u16* A0, const u16* A1,
    const u16* B0a, const u16* B0b,
    const u16* B1a, const u16* B1b,
    const u16* B2a, const u16* B2b,
    int n0, int n1,
    u16* Cb, float* Cf,
    int M, int N, int K, int ldc)
{
    const int flag = *flagp;
    const u16* A  = flag ? A1 : A0;
    const u16* Bq = flag ? B0b : B0a;
    const u16* Bk = flag ? B1b : B1a;
    const u16* Bv = flag ? B2b : B2a;
    __shared__ u16 Al[128][64];
    __shared__ u16 Bl[128][64];
    const int tid = threadIdx.x;
    const int wave = tid >> 6, lane = tid & 63;
    const int qd = lane >> 4, l16 = lane & 15;
    const int wm = wave & 1, wn = wave >> 1;
    const int m0 = blockIdx.y * 128, nb = blockIdx.x * 128;
    floatx4 acc[4][4];
    floatx4 zf = {0.f, 0.f, 0.f, 0.f};
    for (int mt = 0; mt < 4; ++mt) for (int nt = 0; nt < 4; ++nt) acc[mt][nt] = zf;

    for (int k0 = 0; k0 < K; k0 += 64) {
        #pragma unroll
        for (int it = 0; it < 4; ++it) {
            int idx = tid + it*256;
            int r = idx >> 3, c8 = idx & 7;
            int c8s = c8 ^ (r & 7);                     // source-side swizzle
            gld_lds16(&A[(size_t)(m0 + r)*K + k0 + c8s*8], &Al[r][c8*8]);
            int f = nb + r;
            const u16* Brow = (f < n0) ? (Bq + (size_t)f*K)
                             : (f < n0 + n1) ? (Bk + (size_t)(f - n0)*K)
                             : (Bv + (size_t)(f - n0 - n1)*K);
            gld_lds16(&Brow[k0 + c8s*8], &Bl[r][c8*8]);
        }
        __syncthreads();
        #pragma unroll
        for (int ks = 0; ks < 2; ++ks) {
            bf16x8 af[4], bfr[4];
            #pragma unroll
            for (int mt = 0; mt < 4; ++mt)
                af[mt] = *(const bf16x8*)&Al[wm*64 + mt*16 + l16][((ks*4 + qd) ^ (l16 & 7))*8];
            #pragma unroll
            for (int nt = 0; nt < 4; ++nt)
                bfr[nt] = *(const bf16x8*)&Bl[wn*64 + nt*16 + l16][((ks*4 + qd) ^ (l16 & 7))*8];
            #pragma unroll
            for (int mt = 0; mt < 4; ++mt)
                #pragma unroll
                for (int nt = 0; nt < 4; ++nt)
                    acc[mt][nt] = __builtin_amdgcn_mfma_f32_16x16x32_bf16(af[mt], bfr[nt], acc[mt][nt], 0, 0, 0);
        }
        __syncthreads();
    }
    const bool of32 = (Cf != nullptr) && flag;
    #pragma unroll
    for (int mt = 0; mt < 4; ++mt)
        #pragma unroll
        for (int nt = 0; nt < 4; ++nt)
            #pragma unroll
            for (int rg = 0; rg < 4; ++rg) {
                int row = m0 + wm*64 + mt*16 + qd*4 + rg;   // C: row=(lane>>4)*4+reg
                int col = nb + wn*64 + nt*16 + l16;         //    col=lane&15
                float v = acc[mt][nt][rg];
                if (of32) Cf[(size_t)row*ldc + col] = v;
                else      Cb[(size_t)row*ldc + col] = f2bf(v);
            }
}

// ---------------------------------------------------------------- RoPE in-place on Q (slots 0..31) and K (32..39)
__global__ __launch_bounds__(256) void rope_k(const int* flagp, u16* QKV,
                                              const void* cosp, const void* sinp)
{
    const int flag = *flagp;
    long idx = (long)blockIdx.x*256 + threadIdx.x;   // 1024*40*64
    int d = (int)(idx & 63);
    int t = (int)(idx >> 6);
    int slot = t % 40, i = t / 40;
    int col0 = (slot < 32) ? slot*128 : 4096 + (slot - 32)*128;
    size_t base = (size_t)i*6144 + col0;
    float q1 = bf2f(QKV[base + d]), q2 = bf2f(QKV[base + d + 64]);
    float c, s;
    if (flag) { c = ((const float*)cosp)[i*128 + d]; s = ((const float*)sinp)[i*128 + d]; }
    else      { c = bf2f(((const u16*)cosp)[i*128 + d]); s = bf2f(((const u16*)sinp)[i*128 + d]); }
    QKV[base + d]      = f2bf(q1*c - q2*s);
    QKV[base + d + 64] = f2bf(q2*c + q1*s);
}

// ---------------------------------------------------------------- V transpose: VT[g][d][j] = V[j][g][d]
__global__ __launch_bounds__(256) void vtrans_k(const u16* QKV, u16* VT)
{
    const int b = blockIdx.x;            // 256 blocks: g(8) x dblk(2) x jblk(16)
    const int g = b >> 5, db = (b >> 4) & 1, jb = b & 15;
    __shared__ u16 t[64][72];
    const int tid = threadIdx.x;
    #pragma unroll
    for (int it = 0; it < 2; ++it) {
        int idx = tid + it*256;
        int jj = idx >> 3, c8 = idx & 7;
        uint4 v = *(const uint4*)&QKV[(size_t)(jb*64 + jj)*6144 + 5120 + g*128 + db*64 + c8*8];
        *(uint4*)&t[jj][c8*8] = v;
    }
    __syncthreads();
    #pragma unroll
    for (int it = 0; it < 2; ++it) {
        int idx = tid + it*256;
        int dd = idx >> 3, c8 = idx & 7;
        u16 tmp[8];
        #pragma unroll
        for (int e = 0; e < 8; ++e) tmp[e] = t[c8*8 + e][dd];
        *(uint4*)&VT[(size_t)(g*128 + db*64 + dd)*1024 + jb*64 + c8*8] = *(uint4*)tmp;
    }
}

// ---------------------------------------------------------------- head-0 causal row max (scaled)
__global__ __launch_bounds__(256) void rowmax0_k(const u16* QKV, float* rowmax0)
{
    const int i = blockIdx.x;
    __shared__ float Qs[128];
    __shared__ float wm4[4];
    const int tid = threadIdx.x, wave = tid >> 6, lane = tid & 63;
    if (tid < 16) {
        uint4 v = *(const uint4*)&QKV[(size_t)i*6144 + tid*8];
        Qs[tid*8+0] = bf2f((u16)(v.x & 0xffff)); Qs[tid*8+1] = bf2f((u16)(v.x >> 16));
        Qs[tid*8+2] = bf2f((u16)(v.y & 0xffff)); Qs[tid*8+3] = bf2f((u16)(v.y >> 16));
        Qs[tid*8+4] = bf2f((u16)(v.z & 0xffff)); Qs[tid*8+5] = bf2f((u16)(v.z >> 16));
        Qs[tid*8+6] = bf2f((u16)(v.w & 0xffff)); Qs[tid*8+7] = bf2f((u16)(v.w >> 16));
    }
    __syncthreads();
    float mx = -3.0e38f;
    for (int j = tid; j <= i; j += 256) {
        const u16* Kr = &QKV[(size_t)j*6144 + 4096];   // kv head 0
        float acc = 0.f;
        #pragma unroll
        for (int c8 = 0; c8 < 16; ++c8) {
            uint4 v = *(const uint4*)&Kr[c8*8];
            acc += Qs[c8*8+0]*bf2f((u16)(v.x & 0xffff)) + Qs[c8*8+1]*bf2f((u16)(v.x >> 16));
            acc += Qs[c8*8+2]*bf2f((u16)(v.y & 0xffff)) + Qs[c8*8+3]*bf2f((u16)(v.y >> 16));
            acc += Qs[c8*8+4]*bf2f((u16)(v.z & 0xffff)) + Qs[c8*8+5]*bf2f((u16)(v.z >> 16));
            acc += Qs[c8*8+6]*bf2f((u16)(v.w & 0xffff)) + Qs[c8*8+7]*bf2f((u16)(v.w >> 16));
        }
        mx = fmaxf(mx, acc * SCALE);
    }
    #pragma unroll
    for (int off = 1; off < 64; off <<= 1) mx = fmaxf(mx, __shfl_xor(mx, off, 64));
    if (lane == 0) wm4[wave] = mx;
    __syncthreads();
    if (tid == 0) rowmax0[i] = fmaxf(fmaxf(wm4[0], wm4[1]), fmaxf(wm4[2], wm4[3]));
}

// ---------------------------------------------------------------- scores (MFMA, direct-global) -> Sg fp16 + count
// Ragged layout: per (h,rb): 16 rows x jtc*64 fp16; jtc(rb)=(rb>>2)+1;
// prefix(rb)=jtc*(2*(rb>>2)+(rb&3)) row-tiles of 1024 elems; per head sum = 544*1024.
__global__ __launch_bounds__(256) void score_count(
    const u16* QKV, const float* rowmax0, int* count_sum, u16* Sg)
{
    const int bid = blockIdx.x;
    const int h = bid >> 6, rb = 63 - (bid & 63);   // heavy row-blocks first
    const int r0 = rb * 16, g = h >> 2;
    const int q4 = rb >> 2, rm4 = rb & 3;
    const int jtc = q4 + 1;                          // == (r0+16+63)>>6
    const int jt64 = jtc * 64;
    const size_t sbase = ((size_t)h*544 + (size_t)jtc*(2*q4 + rm4)) * 1024;
    const int tid = threadIdx.x, wave = tid >> 6, lane = tid & 63;
    const int qd = lane >> 4, l16 = lane & 15;
    __shared__ u16 SP[16][1032];
    __shared__ int redcnt[4][16];

    bf16x8 af[4];
    #pragma unroll
    for (int ks = 0; ks < 4; ++ks)
        af[ks] = *(const bf16x8*)&QKV[(size_t)(r0 + l16)*6144 + h*128 + ks*32 + qd*8];

    float rm0[4]; int runcnt[4];
    #pragma unroll
    for (int rg = 0; rg < 4; ++rg) {
        runcnt[rg] = 0;
        rm0[rg] = rowmax0[r0 + qd*4 + rg] - 5.0f;
    }

    #pragma unroll 2
    for (int ct = 0; ct < jtc; ++ct) {
        const int jc = ct*64 + wave*16 + l16;
        floatx4 sa = {0.f, 0.f, 0.f, 0.f};
        #pragma unroll
        for (int ks = 0; ks < 4; ++ks) {
            bf16x8 bfr = *(const bf16x8*)&QKV[(size_t)jc*6144 + 4096 + g*128 + ks*32 + qd*8];
            sa = __builtin_amdgcn_mfma_f32_16x16x32_bf16(af[ks], bfr, sa, 0, 0, 0);
        }
        #pragma unroll
        for (int rg = 0; rg < 4; ++rg) {
            float s = sa[rg] * SCALE;
            int i = r0 + qd*4 + rg;
            if (jc <= i && s >= rm0[rg]) runcnt[rg]++;
            SP[qd*4 + rg][jc] = f2h_bits(s);
        }
    }
    #pragma unroll
    for (int off = 1; off < 16; off <<= 1)
        #pragma unroll
        for (int rg = 0; rg < 4; ++rg)
            runcnt[rg] += __shfl_xor(runcnt[rg], off, 64);
    if (l16 == 0)
        #pragma unroll
        for (int rg = 0; rg < 4; ++rg)
            redcnt[wave][qd*4 + rg] = runcnt[rg];
    __syncthreads();
    // coalesced flush: each wave stores 4 rows, 64 lanes x uint4 = 1KB/instr
    #pragma unroll
    for (int mm = 0; mm < 4; ++mm) {
        const int m = wave*4 + mm;
        for (int c = lane; c < jtc*8; c += 64)
            *(uint4*)&Sg[sbase + (size_t)m*jt64 + c*8] = *(const uint4*)&SP[m][c*8];
    }
    if (tid < 16) {
        int c = redcnt[0][tid] + redcnt[1][tid] + redcnt[2][tid] + redcnt[3][tid];
        atomicAdd(&count_sum[r0 + tid], c);
    }
}

// ---------------------------------------------------------------- select_attn helpers
// phase B: per wave-row exact top-k (keys in 16 VGPRs) + probs into SPt
__device__ __forceinline__ void phase_b(u16 (*SPt)[1032], float* denomt,
                                        const int* kc, int r0, int jtc,
                                        int wave, int lane)
{
    #pragma unroll
    for (int batch = 0; batch < 4; ++batch) {
        const int m = batch*4 + wave;      // rows are wave-exclusive
        const int i = r0 + m, n = i + 1;
        const bool full = (i < FETCH_MAX);

        u32 key[16];
        #pragma unroll
        for (int c = 0; c < 16; ++c) {
            u32 kk = 0u;
            if (c*64 < n) {                       // wave-uniform guard
                int j = c*64 + lane;
                u32 t = h2key(SPt[m][j]);
                kk = (j < n) ? t : 0u;
            }
            key[c] = kk;
        }

        u32 kmax = key[0];
        #pragma unroll
        for (int c = 1; c < 16; ++c) kmax = (key[c] > kmax) ? key[c] : kmax;
        #pragma unroll
        for (int off = 1; off < 64; off <<= 1) {
            u32 o = (u32)__shfl_xor((int)kmax, off, 64);
            kmax = (o > kmax) ? o : kmax;
        }
        const float rmax = h_bits2f(key2h(kmax));

        u32 Kstar = 0; int quota = 0;
        if (!full) {
            int k = kc[batch] >> 5;               // floor(mean over 32 heads)
            if (k > FETCH_MAX) k = FETCH_MAX;
            if (k < 1) k = 1;
            u32 t = 0;
            #pragma unroll 1
            for (int bit = 15; bit >= 0; --bit) {
                u32 tc = t | (1u << bit);
                int cnt = 0;
                #pragma unroll
                for (int c = 0; c < 16; ++c)
                    if (c*64 < n)
                        cnt += __popcll(__ballot(key[c] >= tc));
                if (cnt >= k) t = tc;
            }
            Kstar = t;
            int cntgt = 0;
            #pragma unroll
            for (int c = 0; c < 16; ++c)
                if (c*64 < n)
                    cntgt += __popcll(__ballot(key[c] > Kstar));
            quota = k - cntgt;
        }

        float psum = 0.f; int eqbase = 0;
        #pragma unroll
        for (int c = 0; c < 16; ++c) {
            if (c < jtc) {                         // block-uniform
                float p = 0.f;
                if (c*64 < n) {
                    int j = c*64 + lane;
                    bool valid = (j < n);
                    bool keep;
                    if (full) keep = valid;
                    else {
                        bool eq = valid && (key[c] == Kstar);
                        unsigned long long em = __ballot(eq);
                        int rk = eqbase + __popcll(em & ((1ull << lane) - 1ull));
                        keep = valid && ((key[c] > Kstar) || (eq && rk < quota));
                        eqbase += __popcll(em);
                    }
                    if (keep) p = __expf(h_bits2f(key2h(key[c])) - rmax);
                }
                psum += p;
                SPt[m][c*64 + lane] = f2bf(p);
            }
        }
        #pragma unroll
        for (int off = 1; off < 64; off <<= 1) psum += __shfl_xor(psum, off, 64);
        if (lane == 0) denomt[m] = psum;
    }
}

// phase C: PV from SPt probs x pre-transposed VT
__device__ __forceinline__ void phase_c(const u16 (*SPt)[1032], const float* denomt,
                                        const u16* VTg, u16* attn, int r0, int jtc,
                                        int h, int wave, int lane)
{
    const int qd = lane >> 4, l16 = lane & 15;
    floatx4 oacc[2];
    floatx4 zf = {0.f, 0.f, 0.f, 0.f};
    oacc[0] = zf; oacc[1] = zf;
    #pragma unroll 2
    for (int jt = 0; jt < jtc; ++jt) {
        #pragma unroll
        for (int ks = 0; ks < 2; ++ks) {
            bf16x8 pa = *(const bf16x8*)&SPt[l16][jt*64 + ks*32 + qd*8];
            #pragma unroll
            for (int nt = 0; nt < 2; ++nt) {
                bf16x8 bv = *(const bf16x8*)&VTg[(size_t)(wave*32 + nt*16 + l16)*1024 + jt*64 + ks*32 + qd*8];
                oacc[nt] = __builtin_amdgcn_mfma_f32_16x16x32_bf16(pa, bv, oacc[nt], 0, 0, 0);
            }
        }
    }
    #pragma unroll
    for (int nt = 0; nt < 2; ++nt)
        #pragma unroll
        for (int rg = 0; rg < 4; ++rg) {
            int m = qd*4 + rg;
            float v = oacc[nt][rg] / denomt[m];
            attn[(size_t)(r0 + m)*4096 + (h << 7) + wave*32 + nt*16 + l16] = f2bf(v);
        }
}

// ---------------------------------------------------------------- fused: paired tasks, dbuf staging
// v4: each block handles TWO (h,rb) tasks -- (h, 63-p) and (h, p), whose tile counts
// always sum to 17 (uniform grid, no tail). SP double-buffered (66KB, 2 blocks/CU);
// task1's global_load_lds staging is issued BEFORE task0's phase B so the HBM burst
// hides under the bisection VALU. count_sum preloaded + asm-pinned so the compiler's
// vmcnt wait lands before the async stage, not inside phase B.
__global__ __launch_bounds__(256, 2) void select_attn(
    const u16* Sg, const u16* VT, const int* count_sum, u16* attn)
{
    const int b = blockIdx.x;            // 1024 blocks: h(32) x p(32)
    const int h = b >> 5, p = b & 31, g = h >> 2;
    const int rb0 = 63 - p, rb1 = p;
    const int q40 = rb0 >> 2, jtc0 = q40 + 1, r00 = rb0 * 16;
    const int q41 = rb1 >> 2, jtc1 = q41 + 1, r01 = rb1 * 16;
    const size_t sb0 = ((size_t)h*544 + (size_t)jtc0*(2*q40 + (rb0 & 3))) * 1024;
    const size_t sb1 = ((size_t)h*544 + (size_t)jtc1*(2*q41 + (rb1 & 3))) * 1024;
    const int tid = threadIdx.x, wave = tid >> 6, lane = tid & 63;
    __shared__ u16 SP[2][16][1032];
    __shared__ float denom[2][16];
    const u16* VTg = VT + (size_t)g*128*1024;

    // stage task0 (async gld_lds; wave w stages rows 4w..4w+3; dest = base + lane*16)
    #pragma unroll
    for (int mm = 0; mm < 4; ++mm) {
        const int m = wave*4 + mm;
        for (int c = lane; c < jtc0*8; c += 64)
            gld_lds16(&Sg[sb0 + (size_t)m*(jtc0*64) + (size_t)c*8], &SP[0][m][c*8]);
    }
    // preload counts for both tasks, pin them so the vmcnt wait happens HERE
    int kc0[4], kc1[4];
    #pragma unroll
    for (int bb = 0; bb < 4; ++bb) {
        kc0[bb] = count_sum[r00 + bb*4 + wave];
        kc1[bb] = count_sum[r01 + bb*4 + wave];
    }
    #pragma unroll
    for (int bb = 0; bb < 4; ++bb)
        asm volatile("" : "+v"(kc0[bb]), "+v"(kc1[bb]));
    __syncthreads();                                  // SP[0] ready

    // stage task1 (async, in flight under phase B of task0)
    #pragma unroll
    for (int mm = 0; mm < 4; ++mm) {
        const int m = wave*4 + mm;
        for (int c = lane; c < jtc1*8; c += 64)
            gld_lds16(&Sg[sb1 + (size_t)m*(jtc1*64) + (size_t)c*8], &SP[1][m][c*8]);
    }

    phase_b(SP[0], denom[0], kc0, r00, jtc0, wave, lane);
    __syncthreads();                                  // drains stage(1); SP[0] probs visible

    phase_c(SP[0], denom[0], VTg, attn, r00, jtc0, h, wave, lane);
    phase_b(SP[1], denom[1], kc1, r01, jtc1, wave, lane);   // scheduler may overlap with C0
    __syncthreads();                                  // SP[1] probs visible

    phase_c(SP[1], denom[1], VTg, attn, r01, jtc1, h, wave, lane);
}

// ---------------------------------------------------------------- host launch
extern "C" void kernel_launch(void* const* d_in, const int* in_sizes, int n_in,
                              void* d_out, int out_size, void* d_ws, size_t ws_size,
                              hipStream_t stream)
{
    const void* hs = d_in[0];
    const void* cs = d_in[1];
    const void* sn = d_in[2];
    const void* wq = d_in[3];
    const void* wk = d_in[4];
    const void* wv = d_in[5];
    const void* wo = d_in[6];
    (void)in_sizes; (void)n_in; (void)out_size; (void)ws_size;

    unsigned char* W = (unsigned char*)d_ws;
    int*    flag  = (int*)   (W);
    int*    cnt   = (int*)   (W + 256);
    float*  rmax0 = (float*) (W + 4608);
    u16*    qkv   = (u16*)   (W + 139776);        // [1024][6144] bf16
    u16*    attn  = (u16*)   (W + 12722688);      // [1024][4096] bf16
    // converted-input buffers (only touched when inputs are fp32; flag=0 path never writes them)
    u16*    chs   = (u16*)   (W + 21111296);
    u16*    cwq   = (u16*)   (W + 29499904);
    u16*    cwk   = (u16*)   (W + 63054336);
    u16*    cwv   = (u16*)   (W + 71442944);
    u16*    cwo   = (u16*)   (W + 79831552);
    // VT[8][128][1024] bf16 (2 MB) reuses the chs region: chs is dead after the QKV GEMM.
    u16*    vt    = (u16*)   (W + 21111296);
    // ragged fp16 score buffer (34 MB = 32 heads * 544 * 1024 * 2B) reuses cwq/cwk/cwv,
    // all dead after the QKV GEMM; ends at 65.2 MB, below cwo at 79.8 MB.
    u16*    scrs  = (u16*)   (W + 29499904);

    detect_k<<<1, 64, 0, stream>>>((const u32*)cs, flag);
    convert_k<<<4096, 256, 0, stream>>>(flag, (const float*)hs, (const float*)wq,
                                        (const float*)wk, (const float*)wv, (const float*)wo,
                                        chs, cwq, cwk, cwv, cwo);
    // fused QKV projection: C[1024][6144]
    gemm_bt<<<dim3(48, 8), 256, 0, stream>>>(flag,
        (const u16*)hs, chs,
        (const u16*)wq, cwq, (const u16*)wk, cwk, (const u16*)wv, cwv,
        4096, 1024, qkv, nullptr, 1024, 6144, 4096, 6144);
    vtrans_k<<<256, 256, 0, stream>>>(qkv, vt);   // V is rope-free: safe right after GEMM
    rope_k<<<10240, 256, 0, stream>>>(flag, qkv, cs, sn);
    rowmax0_k<<<1024, 256, 0, stream>>>(qkv, rmax0);
    zero_k<<<4, 256, 0, stream>>>(cnt, 1024);
    score_count<<<2048, 256, 0, stream>>>(qkv, rmax0, cnt, scrs);
    select_attn<<<1024, 256, 0, stream>>>(scrs, vt, cnt, attn);
    // output projection
    gemm_bt<<<dim3(32, 8), 256, 0, stream>>>(flag,
        attn, attn,
        (const u16*)wo, cwo, (const u16*)wo, cwo, (const u16*)wo, cwo,
        4096, 4096, (u16*)d_out, (float*)d_out, 1024, 4096, 4096, 4096);
}

// Round 6
// 526.906 us; speedup vs baseline: 1.1474x; 1.0837x over previous
//
#include <hip/hip_runtime.h>
#include <hip/hip_bf16.h>
#include <hip/hip_fp16.h>

typedef unsigned int u32;
typedef unsigned short u16;
typedef __bf16 bf16x8 __attribute__((ext_vector_type(8)));
typedef float floatx4 __attribute__((ext_vector_type(4)));

#define SCALE 0.08838834764831845f
#define FETCH_MAX 204

__device__ __forceinline__ float bf2f(u16 u) {
    union { u32 i; float f; } v; v.i = ((u32)u) << 16; return v.f;
}
__device__ __forceinline__ u16 f2bf(float f) {
    union { float f; u32 i; } v; v.f = f;
    u32 r = v.i + 0x7FFFu + ((v.i >> 16) & 1u);
    return (u16)(r >> 16);
}
__device__ __forceinline__ u16 f2h_bits(float f) {
    __half h = __float2half(f);
    union { __half h; u16 u; } v; v.h = h; return v.u;
}
__device__ __forceinline__ float h_bits2f(u16 u) {
    union { __half h; u16 u; } v; v.u = u; return __half2float(v.h);
}
__device__ __forceinline__ u32 h2key(u16 hb) {     // order-preserving fp16 -> u16 key
    return (u32)(u16)(hb ^ ((hb & 0x8000u) ? 0xFFFFu : 0x8000u));
}
__device__ __forceinline__ u16 key2h(u32 k) {      // inverse of h2key
    return (u16)((k & 0x8000u) ? (k ^ 0x8000u) : (k ^ 0xFFFFu));
}
// async global->LDS, 16B per lane; LDS dest must be wave-uniform base + lane*16
__device__ __forceinline__ void gld_lds16(const void* g, void* l) {
    __builtin_amdgcn_global_load_lds(
        (const __attribute__((address_space(1))) void*)g,
        (__attribute__((address_space(3))) void*)l, 16, 0, 0);
}

// ---------------------------------------------------------------- detect input dtype
__global__ void detect_k(const u32* cosw, int* flag) {
    if (threadIdx.x == 0 && blockIdx.x == 0)
        *flag = (cosw[0] == 0x3F800000u) ? 1 : 0;   // 1 = inputs are fp32
}

__global__ __launch_bounds__(256) void zero_k(int* p, int n) {
    int i = blockIdx.x * 256 + threadIdx.x;
    if (i < n) p[i] = 0;
}

// ---------------------------------------------------------------- convert (fp32 -> bf16), only when flag==1
__global__ __launch_bounds__(256) void convert_k(
    const int* flagp, const float* hs, const float* wq, const float* wk,
    const float* wv, const float* wo,
    u16* chs, u16* cwq, u16* cwk, u16* cwv, u16* cwo)
{
    if (*flagp == 0) return;
    const long S0 = 4194304/4, S1 = 16777216/4, S2 = 4194304/4, S3 = 4194304/4, S4 = 16777216/4;
    const long total = S0+S1+S2+S3+S4;
    for (long idx = (long)blockIdx.x*256 + threadIdx.x; idx < total; idx += (long)gridDim.x*256) {
        const float* src; u16* dst; long o = idx;
        if (o < S0)            { src = hs; dst = chs; }
        else if ((o -= S0) < S1) { src = wq; dst = cwq; }
        else if ((o -= S1) < S2) { src = wk; dst = cwk; }
        else if ((o -= S2) < S3) { src = wv; dst = cwv; }
        else                   { o -= S3; src = wo; dst = cwo; }
        float4 v = ((const float4*)src)[o];
        u32 lo = (u32)f2bf(v.x) | ((u32)f2bf(v.y) << 16);
        u32 hi = (u32)f2bf(v.z) | ((u32)f2bf(v.w) << 16);
        ((uint2*)dst)[o] = make_uint2(lo, hi);
    }
}

// ---------------------------------------------------------------- GEMM  C[M,N] = A[M,K] * B[N,K]^T
// m97 structure + rule-21 chunk swizzle: LDS dest stays LINEAR (gld_lds requirement),
// the per-lane GLOBAL source chunk is XOR-permuted (c8 ^ r&7), and the fragment read
// applies the same XOR.
__global__ __launch_bounds__(256) void gemm_bt(
    const int* flagp,
    const u16* A0, const u16* A1,
    const u16* B0a, const u16* B0b,
    const u16* B1a, const u16* B1b,
    const u16* B2a, const u16* B2b,
    int n0, int n1,
    u16* Cb, float* Cf,
    int M, int N, int K, int ldc)
{
    const int flag = *flagp;
    const u16* A  = flag ? A1 : A0;
    const u16* Bq = flag ? B0b : B0a;
    const u16* Bk = flag ? B1b : B1a;
    const u16* Bv = flag ? B2b : B2a;
    __shared__ u16 Al[128][64];
    __shared__ u16 Bl[128][64];
    const int tid = threadIdx.x;
    const int wave = tid >> 6, lane = tid & 63;
    const int qd = lane >> 4, l16 = lane & 15;
    const int wm = wave & 1, wn = wave >> 1;
    const int m0 = blockIdx.y * 128, nb = blockIdx.x * 128;
    floatx4 acc[4][4];
    floatx4 zf = {0.f, 0.f, 0.f, 0.f};
    for (int mt = 0; mt < 4; ++mt) for (int nt = 0; nt < 4; ++nt) acc[mt][nt] = zf;

    for (int k0 = 0; k0 < K; k0 += 64) {
        #pragma unroll
        for (int it = 0; it < 4; ++it) {
            int idx = tid + it*256;
            int r = idx >> 3, c8 = idx & 7;
            int c8s = c8 ^ (r & 7);                     // source-side swizzle
            gld_lds16(&A[(size_t)(m0 + r)*K + k0 + c8s*8], &Al[r][c8*8]);
            int f = nb + r;
            const u16* Brow = (f < n0) ? (Bq + (size_t)f*K)
                             : (f < n0 + n1) ? (Bk + (size_t)(f - n0)*K)
                             : (Bv + (size_t)(f - n0 - n1)*K);
            gld_lds16(&Brow[k0 + c8s*8], &Bl[r][c8*8]);
        }
        __syncthreads();
        #pragma unroll
        for (int ks = 0; ks < 2; ++ks) {
            bf16x8 af[4], bfr[4];
            #pragma unroll
            for (int mt = 0; mt < 4; ++mt)
                af[mt] = *(const bf16x8*)&Al[wm*64 + mt*16 + l16][((ks*4 + qd) ^ (l16 & 7))*8];
            #pragma unroll
            for (int nt = 0; nt < 4; ++nt)
                bfr[nt] = *(const bf16x8*)&Bl[wn*64 + nt*16 + l16][((ks*4 + qd) ^ (l16 & 7))*8];
            #pragma unroll
            for (int mt = 0; mt < 4; ++mt)
                #pragma unroll
                for (int nt = 0; nt < 4; ++nt)
                    acc[mt][nt] = __builtin_amdgcn_mfma_f32_16x16x32_bf16(af[mt], bfr[nt], acc[mt][nt], 0, 0, 0);
        }
        __syncthreads();
    }
    const bool of32 = (Cf != nullptr) && flag;
    #pragma unroll
    for (int mt = 0; mt < 4; ++mt)
        #pragma unroll
        for (int nt = 0; nt < 4; ++nt)
            #pragma unroll
            for (int rg = 0; rg < 4; ++rg) {
                int row = m0 + wm*64 + mt*16 + qd*4 + rg;   // C: row=(lane>>4)*4+reg
                int col = nb + wn*64 + nt*16 + l16;         //    col=lane&15
                float v = acc[mt][nt][rg];
                if (of32) Cf[(size_t)row*ldc + col] = v;
                else      Cb[(size_t)row*ldc + col] = f2bf(v);
            }
}

// ---------------------------------------------------------------- RoPE in-place on Q (slots 0..31) and K (32..39)
__global__ __launch_bounds__(256) void rope_k(const int* flagp, u16* QKV,
                                              const void* cosp, const void* sinp)
{
    const int flag = *flagp;
    long idx = (long)blockIdx.x*256 + threadIdx.x;   // 1024*40*64
    int d = (int)(idx & 63);
    int t = (int)(idx >> 6);
    int slot = t % 40, i = t / 40;
    int col0 = (slot < 32) ? slot*128 : 4096 + (slot - 32)*128;
    size_t base = (size_t)i*6144 + col0;
    float q1 = bf2f(QKV[base + d]), q2 = bf2f(QKV[base + d + 64]);
    float c, s;
    if (flag) { c = ((const float*)cosp)[i*128 + d]; s = ((const float*)sinp)[i*128 + d]; }
    else      { c = bf2f(((const u16*)cosp)[i*128 + d]); s = bf2f(((const u16*)sinp)[i*128 + d]); }
    QKV[base + d]      = f2bf(q1*c - q2*s);
    QKV[base + d + 64] = f2bf(q2*c + q1*s);
}

// ---------------------------------------------------------------- V transpose: VT[g][d][j] = V[j][g][d]
__global__ __launch_bounds__(256) void vtrans_k(const u16* QKV, u16* VT)
{
    const int b = blockIdx.x;            // 256 blocks: g(8) x dblk(2) x jblk(16)
    const int g = b >> 5, db = (b >> 4) & 1, jb = b & 15;
    __shared__ u16 t[64][72];
    const int tid = threadIdx.x;
    #pragma unroll
    for (int it = 0; it < 2; ++it) {
        int idx = tid + it*256;
        int jj = idx >> 3, c8 = idx & 7;
        uint4 v = *(const uint4*)&QKV[(size_t)(jb*64 + jj)*6144 + 5120 + g*128 + db*64 + c8*8];
        *(uint4*)&t[jj][c8*8] = v;
    }
    __syncthreads();
    #pragma unroll
    for (int it = 0; it < 2; ++it) {
        int idx = tid + it*256;
        int dd = idx >> 3, c8 = idx & 7;
        u16 tmp[8];
        #pragma unroll
        for (int e = 0; e < 8; ++e) tmp[e] = t[c8*8 + e][dd];
        *(uint4*)&VT[(size_t)(g*128 + db*64 + dd)*1024 + jb*64 + c8*8] = *(uint4*)tmp;
    }
}

// ---------------------------------------------------------------- head-0 causal row max (scaled)
__global__ __launch_bounds__(256) void rowmax0_k(const u16* QKV, float* rowmax0)
{
    const int i = blockIdx.x;
    __shared__ float Qs[128];
    __shared__ float wm4[4];
    const int tid = threadIdx.x, wave = tid >> 6, lane = tid & 63;
    if (tid < 16) {
        uint4 v = *(const uint4*)&QKV[(size_t)i*6144 + tid*8];
        Qs[tid*8+0] = bf2f((u16)(v.x & 0xffff)); Qs[tid*8+1] = bf2f((u16)(v.x >> 16));
        Qs[tid*8+2] = bf2f((u16)(v.y & 0xffff)); Qs[tid*8+3] = bf2f((u16)(v.y >> 16));
        Qs[tid*8+4] = bf2f((u16)(v.z & 0xffff)); Qs[tid*8+5] = bf2f((u16)(v.z >> 16));
        Qs[tid*8+6] = bf2f((u16)(v.w & 0xffff)); Qs[tid*8+7] = bf2f((u16)(v.w >> 16));
    }
    __syncthreads();
    float mx = -3.0e38f;
    for (int j = tid; j <= i; j += 256) {
        const u16* Kr = &QKV[(size_t)j*6144 + 4096];   // kv head 0
        float acc = 0.f;
        #pragma unroll
        for (int c8 = 0; c8 < 16; ++c8) {
            uint4 v = *(const uint4*)&Kr[c8*8];
            acc += Qs[c8*8+0]*bf2f((u16)(v.x & 0xffff)) + Qs[c8*8+1]*bf2f((u16)(v.x >> 16));
            acc += Qs[c8*8+2]*bf2f((u16)(v.y & 0xffff)) + Qs[c8*8+3]*bf2f((u16)(v.y >> 16));
            acc += Qs[c8*8+4]*bf2f((u16)(v.z & 0xffff)) + Qs[c8*8+5]*bf2f((u16)(v.z >> 16));
            acc += Qs[c8*8+6]*bf2f((u16)(v.w & 0xffff)) + Qs[c8*8+7]*bf2f((u16)(v.w >> 16));
        }
        mx = fmaxf(mx, acc * SCALE);
    }
    #pragma unroll
    for (int off = 1; off < 64; off <<= 1) mx = fmaxf(mx, __shfl_xor(mx, off, 64));
    if (lane == 0) wm4[wave] = mx;
    __syncthreads();
    if (tid == 0) rowmax0[i] = fmaxf(fmaxf(wm4[0], wm4[1]), fmaxf(wm4[2], wm4[3]));
}

// ---------------------------------------------------------------- scores (MFMA, direct-global) -> Sg fp16 + count
// Ragged layout: per (h,rb): 16 rows x jtc*64 fp16; jtc(rb)=(rb>>2)+1;
// prefix(rb)=jtc*(2*(rb>>2)+(rb&3)) row-tiles of 1024 elems; per head sum = 544*1024.
__global__ __launch_bounds__(256) void score_count(
    const u16* QKV, const float* rowmax0, int* count_sum, u16* Sg)
{
    const int bid = blockIdx.x;
    const int h = bid >> 6, rb = 63 - (bid & 63);   // heavy row-blocks first
    const int r0 = rb * 16, g = h >> 2;
    const int q4 = rb >> 2, rm4 = rb & 3;
    const int jtc = q4 + 1;                          // == (r0+16+63)>>6
    const int jt64 = jtc * 64;
    const size_t sbase = ((size_t)h*544 + (size_t)jtc*(2*q4 + rm4)) * 1024;
    const int tid = threadIdx.x, wave = tid >> 6, lane = tid & 63;
    const int qd = lane >> 4, l16 = lane & 15;
    __shared__ u16 SP[16][1032];
    __shared__ int redcnt[4][16];

    bf16x8 af[4];
    #pragma unroll
    for (int ks = 0; ks < 4; ++ks)
        af[ks] = *(const bf16x8*)&QKV[(size_t)(r0 + l16)*6144 + h*128 + ks*32 + qd*8];

    float rm0[4]; int runcnt[4];
    #pragma unroll
    for (int rg = 0; rg < 4; ++rg) {
        runcnt[rg] = 0;
        rm0[rg] = rowmax0[r0 + qd*4 + rg] - 5.0f;
    }

    #pragma unroll 2
    for (int ct = 0; ct < jtc; ++ct) {
        const int jc = ct*64 + wave*16 + l16;
        floatx4 sa = {0.f, 0.f, 0.f, 0.f};
        #pragma unroll
        for (int ks = 0; ks < 4; ++ks) {
            bf16x8 bfr = *(const bf16x8*)&QKV[(size_t)jc*6144 + 4096 + g*128 + ks*32 + qd*8];
            sa = __builtin_amdgcn_mfma_f32_16x16x32_bf16(af[ks], bfr, sa, 0, 0, 0);
        }
        #pragma unroll
        for (int rg = 0; rg < 4; ++rg) {
            float s = sa[rg] * SCALE;
            int i = r0 + qd*4 + rg;
            if (jc <= i && s >= rm0[rg]) runcnt[rg]++;
            SP[qd*4 + rg][jc] = f2h_bits(s);
        }
    }
    #pragma unroll
    for (int off = 1; off < 16; off <<= 1)
        #pragma unroll
        for (int rg = 0; rg < 4; ++rg)
            runcnt[rg] += __shfl_xor(runcnt[rg], off, 64);
    if (l16 == 0)
        #pragma unroll
        for (int rg = 0; rg < 4; ++rg)
            redcnt[wave][qd*4 + rg] = runcnt[rg];
    __syncthreads();
    // coalesced flush: each wave stores 4 rows, 64 lanes x uint4 = 1KB/instr
    #pragma unroll
    for (int mm = 0; mm < 4; ++mm) {
        const int m = wave*4 + mm;
        for (int c = lane; c < jtc*8; c += 64)
            *(uint4*)&Sg[sbase + (size_t)m*jt64 + c*8] = *(const uint4*)&SP[m][c*8];
    }
    if (tid < 16) {
        int c = redcnt[0][tid] + redcnt[1][tid] + redcnt[2][tid] + redcnt[3][tid];
        atomicAdd(&count_sum[r0 + tid], c);
    }
}

// ---------------------------------------------------------------- select_attn helpers
// phase B: per wave-row exact top-k (keys in 16 VGPRs) + probs into SPt
__device__ __forceinline__ void phase_b(u16 (*SPt)[1032], float* denomt,
                                        const int* kc, int r0, int jtc,
                                        int wave, int lane)
{
    #pragma unroll
    for (int batch = 0; batch < 4; ++batch) {
        const int m = batch*4 + wave;      // rows are wave-exclusive
        const int i = r0 + m, n = i + 1;
        const bool full = (i < FETCH_MAX);

        u32 key[16];
        #pragma unroll
        for (int c = 0; c < 16; ++c) {
            u32 kk = 0u;
            if (c*64 < n) {                       // wave-uniform guard
                int j = c*64 + lane;
                u32 t = h2key(SPt[m][j]);
                kk = (j < n) ? t : 0u;
            }
            key[c] = kk;
        }

        u32 kmax = key[0];
        #pragma unroll
        for (int c = 1; c < 16; ++c) kmax = (key[c] > kmax) ? key[c] : kmax;
        #pragma unroll
        for (int off = 1; off < 64; off <<= 1) {
            u32 o = (u32)__shfl_xor((int)kmax, off, 64);
            kmax = (o > kmax) ? o : kmax;
        }
        const float rmax = h_bits2f(key2h(kmax));

        u32 Kstar = 0; int quota = 0;
        if (!full) {
            int k = kc[batch] >> 5;               // floor(mean over 32 heads)
            if (k > FETCH_MAX) k = FETCH_MAX;
            if (k < 1) k = 1;
            u32 t = 0;
            #pragma unroll 1
            for (int bit = 15; bit >= 0; --bit) {
                u32 tc = t | (1u << bit);
                int cnt = 0;
                #pragma unroll
                for (int c = 0; c < 16; ++c)
                    if (c*64 < n)
                        cnt += __popcll(__ballot(key[c] >= tc));
                if (cnt >= k) t = tc;
            }
            Kstar = t;
            int cntgt = 0;
            #pragma unroll
            for (int c = 0; c < 16; ++c)
                if (c*64 < n)
                    cntgt += __popcll(__ballot(key[c] > Kstar));
            quota = k - cntgt;
        }

        float psum = 0.f; int eqbase = 0;
        #pragma unroll
        for (int c = 0; c < 16; ++c) {
            if (c < jtc) {                         // block-uniform
                float p = 0.f;
                if (c*64 < n) {
                    int j = c*64 + lane;
                    bool valid = (j < n);
                    bool keep;
                    if (full) keep = valid;
                    else {
                        bool eq = valid && (key[c] == Kstar);
                        unsigned long long em = __ballot(eq);
                        int rk = eqbase + __popcll(em & ((1ull << lane) - 1ull));
                        keep = valid && ((key[c] > Kstar) || (eq && rk < quota));
                        eqbase += __popcll(em);
                    }
                    if (keep) p = __expf(h_bits2f(key2h(key[c])) - rmax);
                }
                psum += p;
                SPt[m][c*64 + lane] = f2bf(p);
            }
        }
        #pragma unroll
        for (int off = 1; off < 64; off <<= 1) psum += __shfl_xor(psum, off, 64);
        if (lane == 0) denomt[m] = psum;
    }
}

// phase C: PV from SPt probs x pre-transposed VT
__device__ __forceinline__ void phase_c(const u16 (*SPt)[1032], const float* denomt,
                                        const u16* VTg, u16* attn, int r0, int jtc,
                                        int h, int wave, int lane)
{
    const int qd = lane >> 4, l16 = lane & 15;
    floatx4 oacc[2];
    floatx4 zf = {0.f, 0.f, 0.f, 0.f};
    oacc[0] = zf; oacc[1] = zf;
    #pragma unroll 2
    for (int jt = 0; jt < jtc; ++jt) {
        #pragma unroll
        for (int ks = 0; ks < 2; ++ks) {
            bf16x8 pa = *(const bf16x8*)&SPt[l16][jt*64 + ks*32 + qd*8];
            #pragma unroll
            for (int nt = 0; nt < 2; ++nt) {
                bf16x8 bv = *(const bf16x8*)&VTg[(size_t)(wave*32 + nt*16 + l16)*1024 + jt*64 + ks*32 + qd*8];
                oacc[nt] = __builtin_amdgcn_mfma_f32_16x16x32_bf16(pa, bv, oacc[nt], 0, 0, 0);
            }
        }
    }
    #pragma unroll
    for (int nt = 0; nt < 2; ++nt)
        #pragma unroll
        for (int rg = 0; rg < 4; ++rg) {
            int m = qd*4 + rg;
            float v = oacc[nt][rg] / denomt[m];
            attn[(size_t)(r0 + m)*4096 + (h << 7) + wave*32 + nt*16 + l16] = f2bf(v);
        }
}

// ---------------------------------------------------------------- fused: paired tasks, ONE SP buffer
// v5: uniform 17-tile blocks (task0 = (h,63-p), task1 = (h,p)) but SINGLE 33KB SP ->
// 4 blocks/CU; 1024 blocks = whole grid co-resident, zero tail. Task1 (<=8 tiles =
// 4 uint4/thread) is T14-prefetched into registers right after the first barrier
// (asm-pinned so the loads can't sink); its vmcnt drain happens naturally at C0's
// VT loads -- hidden under phase B's ~30us of VALU. R5's dbuf (2 blocks/CU) showed
// occupancy > stage-overlap for this VALU-latency-bound kernel.
__global__ __launch_bounds__(256, 4) void select_attn(
    const u16* Sg, const u16* VT, const int* count_sum, u16* attn)
{
    const int b = blockIdx.x;            // 1024 blocks: h(32) x p(32)
    const int h = b >> 5, p = b & 31, g = h >> 2;
    const int rb0 = 63 - p, rb1 = p;
    const int q40 = rb0 >> 2, jtc0 = q40 + 1, r00 = rb0 * 16;   // jtc0 in 9..16
    const int q41 = rb1 >> 2, jtc1 = q41 + 1, r01 = rb1 * 16;   // jtc1 in 1..8
    const size_t sb0 = ((size_t)h*544 + (size_t)jtc0*(2*q40 + (rb0 & 3))) * 1024;
    const size_t sb1 = ((size_t)h*544 + (size_t)jtc1*(2*q41 + (rb1 & 3))) * 1024;
    const int tid = threadIdx.x, wave = tid >> 6, lane = tid & 63;
    __shared__ u16 SP[16][1032];
    __shared__ float denom[2][16];
    const u16* VTg = VT + (size_t)g*128*1024;

    // stage task0 via async gld_lds (dest = wave-uniform base + lane*16)
    #pragma unroll
    for (int mm = 0; mm < 4; ++mm) {
        const int m = wave*4 + mm;
        for (int c = lane; c < jtc0*8; c += 64)
            gld_lds16(&Sg[sb0 + (size_t)m*(jtc0*64) + (size_t)c*8], &SP[m][c*8]);
    }
    // preload counts for both tasks, pin so the vmcnt wait lands here
    int kc0[4], kc1[4];
    #pragma unroll
    for (int bb = 0; bb < 4; ++bb) {
        kc0[bb] = count_sum[r00 + bb*4 + wave];
        kc1[bb] = count_sum[r01 + bb*4 + wave];
        asm volatile("" : "+v"(kc0[bb]), "+v"(kc1[bb]));
    }
    __syncthreads();                                  // SP = task0 scores

    // T14 prefetch: task1's whole score block into 16 VGPRs (jtc1*8 <= 64)
    uint4 rv[4];
    #pragma unroll
    for (int mm = 0; mm < 4; ++mm) {
        const int m = wave*4 + mm;
        rv[mm] = make_uint4(0u, 0u, 0u, 0u);
        if (lane < jtc1*8)
            rv[mm] = *(const uint4*)&Sg[sb1 + (size_t)m*(jtc1*64) + (size_t)lane*8];
        asm volatile("" : "+v"(rv[mm].x), "+v"(rv[mm].y), "+v"(rv[mm].z), "+v"(rv[mm].w));
    }

    phase_b(SP, denom[0], kc0, r00, jtc0, wave, lane);
    __syncthreads();
    phase_c(SP, denom[0], VTg, attn, r00, jtc0, h, wave, lane);
    __syncthreads();                                  // all SP reads of task0 done

    // land task1 scores from regs
    #pragma unroll
    for (int mm = 0; mm < 4; ++mm) {
        const int m = wave*4 + mm;
        if (lane < jtc1*8)
            *(uint4*)&SP[m][lane*8] = rv[mm];
    }
    __syncthreads();                                  // SP = task1 scores

    phase_b(SP, denom[1], kc1, r01, jtc1, wave, lane);
    __syncthreads();
    phase_c(SP, denom[1], VTg, attn, r01, jtc1, h, wave, lane);
}

// ---------------------------------------------------------------- host launch
extern "C" void kernel_launch(void* const* d_in, const int* in_sizes, int n_in,
                              void* d_out, int out_size, void* d_ws, size_t ws_size,
                              hipStream_t stream)
{
    const void* hs = d_in[0];
    const void* cs = d_in[1];
    const void* sn = d_in[2];
    const void* wq = d_in[3];
    const void* wk = d_in[4];
    const void* wv = d_in[5];
    const void* wo = d_in[6];
    (void)in_sizes; (void)n_in; (void)out_size; (void)ws_size;

    unsigned char* W = (unsigned char*)d_ws;
    int*    flag  = (int*)   (W);
    int*    cnt   = (int*)   (W + 256);
    float*  rmax0 = (float*) (W + 4608);
    u16*    qkv   = (u16*)   (W + 139776);        // [1024][6144] bf16
    u16*    attn  = (u16*)   (W + 12722688);      // [1024][4096] bf16
    // converted-input buffers (only touched when inputs are fp32; flag=0 path never writes them)
    u16*    chs   = (u16*)   (W + 21111296);
    u16*    cwq   = (u16*)   (W + 29499904);
    u16*    cwk   = (u16*)   (W + 63054336);
    u16*    cwv   = (u16*)   (W + 71442944);
    u16*    cwo   = (u16*)   (W + 79831552);
    // VT[8][128][1024] bf16 (2 MB) reuses the chs region: chs is dead after the QKV GEMM.
    u16*    vt    = (u16*)   (W + 21111296);
    // ragged fp16 score buffer (34 MB = 32 heads * 544 * 1024 * 2B) reuses cwq/cwk/cwv,
    // all dead after the QKV GEMM; ends at 65.2 MB, below cwo at 79.8 MB.
    u16*    scrs  = (u16*)   (W + 29499904);

    detect_k<<<1, 64, 0, stream>>>((const u32*)cs, flag);
    convert_k<<<4096, 256, 0, stream>>>(flag, (const float*)hs, (const float*)wq,
                                        (const float*)wk, (const float*)wv, (const float*)wo,
                                        chs, cwq, cwk, cwv, cwo);
    // fused QKV projection: C[1024][6144]
    gemm_bt<<<dim3(48, 8), 256, 0, stream>>>(flag,
        (const u16*)hs, chs,
        (const u16*)wq, cwq, (const u16*)wk, cwk, (const u16*)wv, cwv,
        4096, 1024, qkv, nullptr, 1024, 6144, 4096, 6144);
    vtrans_k<<<256, 256, 0, stream>>>(qkv, vt);   // V is rope-free: safe right after GEMM
    rope_k<<<10240, 256, 0, stream>>>(flag, qkv, cs, sn);
    rowmax0_k<<<1024, 256, 0, stream>>>(qkv, rmax0);
    zero_k<<<4, 256, 0, stream>>>(cnt, 1024);
    score_count<<<2048, 256, 0, stream>>>(qkv, rmax0, cnt, scrs);
    select_attn<<<1024, 256, 0, stream>>>(scrs, vt, cnt, attn);
    // output projection
    gemm_bt<<<dim3(32, 8), 256, 0, stream>>>(flag,
        attn, attn,
        (const u16*)wo, cwo, (const u16*)wo, cwo, (const u16*)wo, cwo,
        4096, 4096, (u16*)d_out, (float*)d_out, 1024, 4096, 4096, 4096);
}